// Round 12
// baseline (347.464 us; speedup 1.0000x reference)
//
#include <hip/hip_runtime.h>

#define N_NODES 10000
#define NEDGE 160000
#define NB 80000  /* N_NODES*BATCH */

typedef unsigned int u32;
typedef unsigned short u16;
typedef __attribute__((ext_vector_type(8))) short short8;
typedef __attribute__((ext_vector_type(4))) float float4v;

__device__ __forceinline__ u16 f2bf(float f) {
    u32 u = __float_as_uint(f);
    return (u16)((u + 0x7fffu + ((u >> 16) & 1u)) >> 16);
}
__device__ __forceinline__ float lo16(u32 u) { return __uint_as_float(u << 16); }
__device__ __forceinline__ float hi16(u32 u) { return __uint_as_float(u & 0xffff0000u); }
__device__ __forceinline__ u32 pack2(float a, float b) {
    return (u32)f2bf(a) | (((u32)f2bf(b)) << 16);
}
__device__ __forceinline__ float fast_tanh(float v) {
    return 1.f - 2.f / (__expf(2.f * v) + 1.f);
}

static const size_t SLAB = (size_t)NB * 64;  // u16 elems per 64-wide slab

// ---------------- prep+count: transpose + bpack12 + bpackP + degree count -----------
__global__ __launch_bounds__(256) void prepcount_kernel(
    const float2* __restrict__ y, u32* __restrict__ X0,
    const float* __restrict__ W_lat, const float* __restrict__ W_units,
    u16* __restrict__ bpk12, const float* __restrict__ W_final, u16* __restrict__ bpkP,
    const int* __restrict__ rows, const int* __restrict__ cols, int* __restrict__ cnt) {
    int b = blockIdx.x, t = threadIdx.x;
    if (b < 10000) {
        int idx = b * 256 + t;  // NB*32 outputs exactly
        int fh = idx & 31;
        int rb = idx >> 5;
        int bb = rb & 7;
        int n = rb >> 3;
        float2 v = y[((size_t)bb * N_NODES + n) * 32 + fh];
        X0[idx] = pack2(v.x, v.y);
    } else if (b < 10240) {
        // fused bpack: K=320 (k=m*64+f, wrow=f*5+m), NOUT=192 (0..63 lat, 64..191 units)
        int idx = (b - 10000) * 256 + t;  // < 61440
        int j = idx & 7;
        int lane = (idx >> 3) & 63;
        int rest = idx >> 9;
        int ct = rest % 12;
        int ks = rest / 12;
        int k = ks * 32 + (lane >> 4) * 8 + j;
        int col = ct * 16 + (lane & 15);
        int wrow = (k % 64) * 5 + (k / 64);
        float v = (col < 64) ? W_lat[wrow * 64 + col] : W_units[wrow * 128 + (col - 64)];
        bpk12[idx] = f2bf(v);
    } else if (b < 10400) {
        // bpackP: K=128, NOUT=320; slot0 = W[:,0]-W[:,2]-W[:,4], slot m>=1 = W[:,m]
        int idx = (b - 10240) * 256 + t;  // < 40960
        int j8 = idx & 7;
        int lane = (idx >> 3) & 63;
        int rest = idx >> 9;
        int ct = rest % 20;
        int ks = rest / 20;
        int k = ks * 32 + (lane >> 4) * 8 + j8;
        int col = ct * 16 + (lane & 15);
        int slot = col >> 6, j = col & 63;
        float v;
        if (slot == 0)
            v = W_final[(k * 5 + 0) * 64 + j] - W_final[(k * 5 + 2) * 64 + j] -
                W_final[(k * 5 + 4) * 64 + j];
        else
            v = W_final[(k * 5 + slot) * 64 + j];
        bpkP[idx] = f2bf(v);
    } else {
        int e = (b - 10400) * 256 + t;  // 625*256 == NEDGE exactly
        atomicAdd(&cnt[cols[e]], 1);            // support1: dst=cols
        atomicAdd(&cnt[N_NODES + rows[e]], 1);  // support2: dst=rows
    }
}

// 80 blocks: per-chunk sums
__global__ void blocksum_kernel(const int* __restrict__ cnt, int* __restrict__ bsums) {
    __shared__ int red[4];
    int arr = blockIdx.x / 40;
    int c = blockIdx.x % 40;
    int idx = c * 256 + threadIdx.x;
    int v = (idx < N_NODES) ? cnt[arr * N_NODES + idx] : 0;
#pragma unroll
    for (int off = 32; off; off >>= 1) v += __shfl_down(v, off, 64);
    int wv = threadIdx.x >> 6, ln = threadIdx.x & 63;
    if (ln == 0) red[wv] = v;
    __syncthreads();
    if (threadIdx.x == 0) bsums[blockIdx.x] = red[0] + red[1] + red[2] + red[3];
}

// 80 blocks: local scan + serial prefix over chunk sums -> rowptr + cursor
__global__ void scanapply_kernel(int* __restrict__ cnt, const int* __restrict__ bsums,
                                 int* __restrict__ rowptr1, int* __restrict__ rowptr2) {
    __shared__ int lds[256];
    int arr = blockIdx.x / 40;
    int c = blockIdx.x % 40;
    int base = 0;
    for (int i = 0; i < c; i++) base += bsums[arr * 40 + i];  // 40-deep serial, L2-hot
    int idx = c * 256 + threadIdx.x;
    bool ok = idx < N_NODES;
    int v = ok ? cnt[arr * N_NODES + idx] : 0;
    int t = threadIdx.x;
    lds[t] = v;
    __syncthreads();
    for (int off = 1; off < 256; off <<= 1) {
        int add = (t >= off) ? lds[t - off] : 0;
        __syncthreads();
        lds[t] += add;
        __syncthreads();
    }
    int excl = lds[t] - v + base;
    if (ok) {
        int* rp = arr ? rowptr2 : rowptr1;
        rp[idx] = excl;
        cnt[arr * N_NODES + idx] = excl;  // cursor
    }
    if (blockIdx.x == 0 && t == 0) {
        rowptr1[N_NODES] = NEDGE;
        rowptr2[N_NODES] = NEDGE;
    }
}

__global__ void scatter_kernel(const int* __restrict__ rows, const int* __restrict__ cols,
                               const float* __restrict__ w1, const float* __restrict__ w2,
                               int* __restrict__ cur1, int* __restrict__ cur2,
                               int2* __restrict__ edges1, int2* __restrict__ edges2) {
    int e = blockIdx.x * 256 + threadIdx.x;
    if (e < NEDGE) {
        int r = rows[e], c = cols[e];
        int p1 = atomicAdd(&cur1[c], 1);
        edges1[p1] = make_int2(r, __float_as_int(w1[e]));
        int p2 = atomicAdd(&cur2[r], 1);
        edges2[p2] = make_int2(c, __float_as_int(w2[e]));
    }
}

// ---------------- SpMM gather: full-width row, 8-deep MLP unroll --------------------
__device__ __forceinline__ void gacc(float* acc, float w, uint4 u) {
    acc[0] += w * lo16(u.x); acc[1] += w * hi16(u.x);
    acc[2] += w * lo16(u.y); acc[3] += w * hi16(u.y);
    acc[4] += w * lo16(u.z); acc[5] += w * hi16(u.z);
    acc[6] += w * lo16(u.w); acc[7] += w * hi16(u.w);
}

__device__ __forceinline__ void gather_row(const u32* __restrict__ Xin,
                                           const int* __restrict__ rp,
                                           const int2* __restrict__ eg,
                                           int n, int lane, float* acc) {
    int e0 = rp[n], e1 = rp[n + 1];
    for (int base = e0; base < e1; base += 64) {
        int m = min(64, e1 - base);
        int2 me = make_int2(0, 0);
        if (lane < m) me = eg[base + lane];
        int j = 0;
        for (; j + 8 <= m; j += 8) {  // 8 independent loads in flight
            int s[8];
            float w[8];
            uint4 u[8];
#pragma unroll
            for (int q = 0; q < 8; q++) {
                s[q] = __shfl(me.x, j + q, 64);
                w[q] = __int_as_float(__shfl(me.y, j + q, 64));
            }
#pragma unroll
            for (int q = 0; q < 8; q++)
                u[q] = *(const uint4*)(Xin + (size_t)s[q] * 256 + lane * 4);
#pragma unroll
            for (int q = 0; q < 8; q++) gacc(acc, w[q], u[q]);
        }
        for (; j < m; j++) {
            int src = __shfl(me.x, j, 64);
            float w = __int_as_float(__shfl(me.y, j, 64));
            uint4 u = *(const uint4*)(Xin + (size_t)src * 256 + lane * 4);
            gacc(acc, w, u);
        }
    }
}

__global__ __launch_bounds__(256) void spmm2_kernel(
    const u32* __restrict__ XinA, const u32* __restrict__ XprevA, u32* __restrict__ XoutA,
    const u32* __restrict__ XinB, const u32* __restrict__ XprevB, u32* __restrict__ XoutB,
    const int* __restrict__ rowptr1, const int2* __restrict__ edges1,
    const int* __restrict__ rowptr2, const int2* __restrict__ edges2,
    float alpha, float beta) {
    int lane = threadIdx.x & 63;
    int v = blockIdx.x * 4 + (threadIdx.x >> 6);
    if (v >= 2 * N_NODES) return;
    bool hB = v >= N_NODES;
    int n = hB ? v - N_NODES : v;
    const u32* Xin = hB ? XinB : XinA;
    const u32* Xprev = hB ? XprevB : XprevA;
    u32* Xout = hB ? XoutB : XoutA;
    const int* rp = hB ? rowptr2 : rowptr1;
    const int2* eg = hB ? edges2 : edges1;

    float acc[8] = {0.f, 0.f, 0.f, 0.f, 0.f, 0.f, 0.f, 0.f};
    gather_row(Xin, rp, eg, n, lane, acc);

    size_t o = (size_t)n * 256 + lane * 4;
    if (beta != 0.f) {
        uint4 p = *(const uint4*)(Xprev + o);
        acc[0] = alpha * acc[0] + beta * lo16(p.x); acc[1] = alpha * acc[1] + beta * hi16(p.x);
        acc[2] = alpha * acc[2] + beta * lo16(p.y); acc[3] = alpha * acc[3] + beta * hi16(p.y);
        acc[4] = alpha * acc[4] + beta * lo16(p.z); acc[5] = alpha * acc[5] + beta * hi16(p.z);
        acc[6] = alpha * acc[6] + beta * lo16(p.w); acc[7] = alpha * acc[7] + beta * hi16(p.w);
    } else {
#pragma unroll
        for (int i = 0; i < 8; i++) acc[i] *= alpha;
    }
    uint4 r;
    r.x = pack2(acc[0], acc[1]);
    r.y = pack2(acc[2], acc[3]);
    r.z = pack2(acc[4], acc[5]);
    r.w = pack2(acc[6], acc[7]);
    *(uint4*)(Xout + o) = r;
}

// final: out = -theta * tanh(Q + S1@T1 + S2@T2), fp32 (B,N,64) layout
__global__ __launch_bounds__(256) void spmm_final_kernel(
    const u32* __restrict__ T1, const u32* __restrict__ T2,
    const u32* __restrict__ Q, const u32* __restrict__ theta,
    const int* __restrict__ rowptr1, const int2* __restrict__ edges1,
    const int* __restrict__ rowptr2, const int2* __restrict__ edges2,
    float* __restrict__ outF) {
    int lane = threadIdx.x & 63;
    int n = blockIdx.x * 4 + (threadIdx.x >> 6);
    if (n >= N_NODES) return;

    float acc[8] = {0.f, 0.f, 0.f, 0.f, 0.f, 0.f, 0.f, 0.f};
    gather_row(T1, rowptr1, edges1, n, lane, acc);
    gather_row(T2, rowptr2, edges2, n, lane, acc);

    size_t o = (size_t)n * 256 + lane * 4;
    uint4 q = *(const uint4*)(Q + o);
    uint4 th = *(const uint4*)(theta + o);
    float res[8];
    res[0] = -lo16(th.x) * fast_tanh(lo16(q.x) + acc[0]);
    res[1] = -hi16(th.x) * fast_tanh(hi16(q.x) + acc[1]);
    res[2] = -lo16(th.y) * fast_tanh(lo16(q.y) + acc[2]);
    res[3] = -hi16(th.y) * fast_tanh(hi16(q.y) + acc[3]);
    res[4] = -lo16(th.z) * fast_tanh(lo16(q.z) + acc[4]);
    res[5] = -hi16(th.z) * fast_tanh(hi16(q.z) + acc[5]);
    res[6] = -lo16(th.w) * fast_tanh(lo16(q.w) + acc[6]);
    res[7] = -hi16(th.w) * fast_tanh(hi16(q.w) + acc[7]);
    int b = lane >> 3;
    int f0 = ((lane * 4) & 31) * 2;
    float* dst = outF + (size_t)b * (N_NODES * 64) + (size_t)n * 64 + f0;
    *(float4*)(dst) = make_float4(res[0], res[1], res[2], res[3]);
    *(float4*)(dst + 4) = make_float4(res[4], res[5], res[6], res[7]);
}

// ---------------- fused GEMM: gemm12 + gemmP via LDS H0 tile ------------------------
// Phase A: [theta|H0] = act(X@W12 + b)  (K=320, NOUT=192); theta->global, H0->LDS tile
// Phase B: P = H0_tile @ WP (+b_lat on slot0 cols)  (K=128, NOUT=320), A from LDS
struct Slabs { const u16* p[5]; };

__global__ __launch_bounds__(256) void gemm12P_kernel(
    Slabs A, const u16* __restrict__ Bp12, const u16* __restrict__ BpP,
    const float* __restrict__ b_lat, const float* __restrict__ b_units,
    u16* __restrict__ theta, u16* __restrict__ P) {
    // per-wave 16x128 H0 tile, row pitch 136 shorts (+16B pad: banks rotate by 4/row)
    __shared__ __align__(16) u16 hls[4][16][136];
    int lane = threadIdx.x & 63;
    int wave = threadIdx.x >> 6;
    int rowBase = blockIdx.x * 64 + wave * 16;
    int mrow = lane & 15;
    int kq = lane >> 4;

    // ---- phase A: K=320 over 5 slabs, 12 col-tiles ----
    float4v acc[12];
#pragma unroll
    for (int c = 0; c < 12; c++) acc[c] = (float4v){0.f, 0.f, 0.f, 0.f};
#pragma unroll
    for (int ks = 0; ks < 10; ks++) {
        int k = ks * 32 + kq * 8;
        int m = k >> 6;
        int koff = k & 63;
        short8 a = *(const short8*)(A.p[m] + (size_t)(rowBase + mrow) * 64 + koff);
        short8 b[12];
#pragma unroll
        for (int ct = 0; ct < 12; ct++)
            b[ct] = *(const short8*)(Bp12 + ((size_t)(ks * 12 + ct) * 64 + lane) * 8);
#pragma unroll
        for (int ct = 0; ct < 12; ct++)
            acc[ct] = __builtin_amdgcn_mfma_f32_16x16x32_bf16(a, b[ct], acc[ct], 0, 0, 0);
    }
#pragma unroll
    for (int ct = 0; ct < 12; ct++) {
        int col = ct * 16 + mrow;
        float bsv = (col < 64) ? b_lat[col] : b_units[col - 64];
#pragma unroll
        for (int i = 0; i < 4; i++) {
            float v = acc[ct][i] + bsv;
            int lr = kq * 4 + i;  // wave-local row 0..15
            if (col < 64) {
                v = 1.f / (1.f + __expf(-v));
                theta[(size_t)(rowBase + lr) * 64 + col] = f2bf(v);
            } else {
                hls[wave][lr][col - 64] = f2bf(fast_tanh(v));
            }
        }
    }
    __syncthreads();  // waves use only their own tile, but ensure LDS writes land

    // ---- phase B: K=128 from LDS, 20 col-tiles in 2 halves ----
#pragma unroll
    for (int ch = 0; ch < 2; ch++) {
        float4v pacc[10];
#pragma unroll
        for (int c = 0; c < 10; c++) pacc[c] = (float4v){0.f, 0.f, 0.f, 0.f};
#pragma unroll
        for (int ks = 0; ks < 4; ks++) {
            short8 a = *(const short8*)(&hls[wave][mrow][ks * 32 + kq * 8]);
            short8 b[10];
#pragma unroll
            for (int ct = 0; ct < 10; ct++)
                b[ct] = *(const short8*)(BpP + ((size_t)((ks * 20 + ch * 10 + ct) * 64 + lane)) * 8);
#pragma unroll
            for (int ct = 0; ct < 10; ct++)
                pacc[ct] = __builtin_amdgcn_mfma_f32_16x16x32_bf16(a, b[ct], pacc[ct], 0, 0, 0);
        }
#pragma unroll
        for (int ct = 0; ct < 10; ct++) {
            int col = (ch * 10 + ct) * 16 + mrow;
            float bsv = (col < 64) ? b_lat[col] : 0.f;
#pragma unroll
            for (int i = 0; i < 4; i++) {
                float v = pacc[ct][i] + bsv;
                int r = rowBase + kq * 4 + i;
                P[(size_t)(col >> 6) * SLAB + (size_t)r * 64 + (col & 63)] = f2bf(v);
            }
        }
    }
}

// ---------------- launch ----------------
extern "C" void kernel_launch(void* const* d_in, const int* in_sizes, int n_in,
                              void* d_out, int out_size, void* d_ws, size_t ws_size,
                              hipStream_t stream) {
    const float2* y    = (const float2*)d_in[0];
    const float* W_lat = (const float*)d_in[1];
    const float* b_lat = (const float*)d_in[2];
    const float* W_units = (const float*)d_in[3];
    const float* b_units = (const float*)d_in[4];
    const float* W_final = (const float*)d_in[5];
    const float* sup1w = (const float*)d_in[6];
    const float* sup2w = (const float*)d_in[7];
    const int* rows    = (const int*)d_in[8];
    const int* cols    = (const int*)d_in[9];
    float* out = (float*)d_out;

    char* ws = (char*)d_ws;
    size_t off = 0;
    auto alloc = [&](size_t bytes) -> void* {
        void* p = ws + off;
        off += (bytes + 511) & ~(size_t)511;
        return p;
    };
    int* rowptr1 = (int*)alloc((N_NODES + 1) * 4);
    int* rowptr2 = (int*)alloc((N_NODES + 1) * 4);
    int* cnt = (int*)alloc((size_t)2 * N_NODES * 4);
    int* bsums = (int*)alloc(80 * 4);
    int2* edges1 = (int2*)alloc((size_t)NEDGE * 8);
    int2* edges2 = (int2*)alloc((size_t)NEDGE * 8);
    u16* bpk12 = (u16*)alloc((size_t)61440 * 2);
    u16* bpkP = (u16*)alloc((size_t)40960 * 2);
    u16* theta = (u16*)alloc((size_t)NB * 64 * 2);
    u16* S = (u16*)alloc((size_t)5 * NB * 64 * 2);   // X-slabs
    u16* P = (u16*)alloc((size_t)5 * NB * 64 * 2);   // Q|P1..P4 (separate: no overlay race)
    u16* T1 = (u16*)alloc((size_t)NB * 64 * 2);
    u16* T2 = (u16*)alloc((size_t)NB * 64 * 2);

    hipMemsetAsync(cnt, 0, (size_t)2 * N_NODES * 4, stream);
    prepcount_kernel<<<11025, 256, 0, stream>>>(y, (u32*)S, W_lat, W_units, bpk12,
                                                W_final, bpkP, rows, cols, cnt);
    blocksum_kernel<<<80, 256, 0, stream>>>(cnt, bsums);
    scanapply_kernel<<<80, 256, 0, stream>>>(cnt, bsums, rowptr1, rowptr2);
    scatter_kernel<<<625, 256, 0, stream>>>(rows, cols, sup1w, sup2w,
                                            cnt, cnt + N_NODES, edges1, edges2);

    // x-side diffusion: X1 = S1@X0, X3 = S2@X0 ; X2 = 2*S1@X1 - X0, X4 = 2*S2@X3 - X0
    const u32* S0 = (const u32*)S;
    u32* X1 = (u32*)(S + 1 * SLAB);
    u32* X2 = (u32*)(S + 2 * SLAB);
    u32* X3 = (u32*)(S + 3 * SLAB);
    u32* X4 = (u32*)(S + 4 * SLAB);
    spmm2_kernel<<<5000, 256, 0, stream>>>(S0, nullptr, X1, S0, nullptr, X3,
                                           rowptr1, edges1, rowptr2, edges2, 1.f, 0.f);
    spmm2_kernel<<<5000, 256, 0, stream>>>(X1, S0, X2, X3, S0, X4,
                                           rowptr1, edges1, rowptr2, edges2, 2.f, -1.f);

    Slabs SX;
    for (int m = 0; m < 5; m++) SX.p[m] = S + (size_t)m * SLAB;
    // fused: theta = sigmoid(X@W_lat+b_lat); H0 = tanh(X@W_units+b_units) (LDS only);
    //        [Q|P1..P4] = H0 @ WP (+b_lat on Q)
    gemm12P_kernel<<<1250, 256, 0, stream>>>(SX, bpk12, bpkP, b_lat, b_units, theta, P);

    const u32* Q  = (const u32*)(P + 0 * SLAB);
    const u32* P1 = (const u32*)(P + 1 * SLAB);
    const u32* P2 = (const u32*)(P + 2 * SLAB);
    const u32* P3 = (const u32*)(P + 3 * SLAB);
    const u32* P4 = (const u32*)(P + 4 * SLAB);
    // T1 = P1 + 2*S1@P2 ; T2 = P3 + 2*S2@P4
    spmm2_kernel<<<5000, 256, 0, stream>>>(P2, P1, (u32*)T1, P4, P3, (u32*)T2,
                                           rowptr1, edges1, rowptr2, edges2, 2.f, 1.f);
    // out = -theta * tanh(Q + S1@T1 + S2@T2)
    spmm_final_kernel<<<2500, 256, 0, stream>>>((const u32*)T1, (const u32*)T2, Q,
                                                (const u32*)theta,
                                                rowptr1, edges1, rowptr2, edges2, out);
}